// Round 14
// baseline (302.847 us; speedup 1.0000x reference)
//
#include <hip/hip_runtime.h>
#include <math.h>

#define BB 8
#define PP 5
#define QQ 75
#define CC 640
#define HW 49
#define NIMG_Q (BB*QQ)     // 600
#define NIMG_S (BB*PP)     // 40
#define NPROB  (BB*QQ*PP)  // 3000
#define TEMP 12.5f

#define CHUNKS 20          // 640 / 32
#define TROW 16            // u32 per tile row (32 f16)
#define TCH  (HW*TROW)     // 784 u32 per chunk
#define TIMG (CHUNKS*TCH)  // 15680 u32 per image
#define SROW 25            // u32 per S row (50 f16, last is zero pad)
#define SPROB (HW*SROW)    // 1225 u32 per problem

// workspace layout (u32/float offsets) -- unchanged; S16 region now unused
#define OFF_SGAP   0
#define OFF_QGAP   (OFF_SGAP  + NIMG_S*CC)
#define OFF_SMEAN  (OFF_QGAP  + NIMG_Q*CC)
#define OFF_SINV   (OFF_SMEAN + NIMG_S*HW)
#define OFF_QMEAN  (OFF_SINV  + NIMG_S*HW)
#define OFF_QINV   (OFF_QMEAN + NIMG_Q*HW)
#define OFF_MARGA  (OFF_QINV  + NIMG_Q*HW)
#define OFF_MARGB  (OFF_MARGA + NPROB*HW)
#define OFF_QT     (OFF_MARGB + NPROB*HW)          // query f16 tiles
#define OFF_ST     (OFF_QT    + NIMG_Q*TIMG)       // support f16 tiles
#define OFF_S16    (OFF_ST    + NIMG_S*TIMG)       // (unused after R14 fusion)
#define OFF_LOGITS (OFF_S16   + NPROB*SPROB)

typedef _Float16 f16x8 __attribute__((ext_vector_type(8)));
typedef float f32x4 __attribute__((ext_vector_type(4)));
#define MFMAH __builtin_amdgcn_mfma_f32_16x16x32_f16

__device__ __forceinline__ float wsum64(float v) {
#pragma unroll
    for (int off = 32; off > 0; off >>= 1) v += __shfl_xor(v, off, 64);
    return v;
}
__device__ __forceinline__ float rlf(float x, int l) {
    return __int_as_float(__builtin_amdgcn_readlane(__float_as_int(x), l));
}
__device__ __forceinline__ unsigned packh2(float a, float b) {
    union { _Float16 h[2]; unsigned u; } pk;
    pk.h[0] = (_Float16)a; pk.h[1] = (_Float16)b;
    return pk.u;
}
// f16 round-trip identical to packh2-then-unpack (fused sinkhorn K init)
__device__ __forceinline__ float f16r(float x) { return (float)(_Float16)x; }

// ---------------- Kernel 0: GAP pre-pass (SGAP + QGAP) ----------------
// R14: QGAP moved out of qry_prep so margb can run inside prep_kernel.
// Identical per-row sum order (8-deep batches + row[48]) -> bitwise same.
__global__ __launch_bounds__(256) void gap_kernel(const float* __restrict__ sup,
                                                  const float* __restrict__ qry,
                                                  float* __restrict__ ws) {
    int img = blockIdx.x;              // 0..639
    int tid = threadIdx.x;
    const float* X;
    float* gap;
    if (img < NIMG_S) {
        X = sup + (size_t)img * CC * HW;
        gap = ws + OFF_SGAP + img * CC;
    } else {
        int q = img - NIMG_S;
        X = qry + (size_t)q * CC * HW;
        gap = ws + OFF_QGAP + q * CC;
    }
    for (int c = tid; c < CC; c += 256) {
        const float* row = X + c * HW;
        float s = 0.f;
#pragma unroll
        for (int g = 0; g < 6; g++) {
            float rv[8];
#pragma unroll
            for (int j = 0; j < 8; j++) rv[j] = row[g * 8 + j];
#pragma unroll
            for (int j = 0; j < 8; j++) s += rv[j];
        }
        s += row[48];
        gap[c] = s * (1.0f / HW);
    }
}

// ---------------- Kernel 1: merged prep: qry(0..599) + sup(600..639) + margb(640..839)
// qry path: R13 minus pass B. sup path: R13. margb path: R12's exact 4-wave
// code (waves 4..7 idle through barriers -> accumulation order preserved).
__global__ __launch_bounds__(512) __attribute__((amdgpu_waves_per_eu(4, 4)))
void prep_kernel(const float* __restrict__ sup, const float* __restrict__ qry,
                 float* __restrict__ ws) {
    int g = blockIdx.x;
    int tid = threadIdx.x;
    int lane = tid & 63;
    int wv = tid >> 6;               // 0..7

    __shared__ float SH[12720];      // 50.9 KB union buffer

    if (g < 600) {
        // ================= query path =================
        float* XSG = SH;                          // 3200
        float (*cs_p)[52] = (float (*)[52])(SH + 3200);
        float (*sq_p)[52] = (float (*)[52])(SH + 3616);
        float (*part)[PP][52] = (float (*)[PP][52])(SH + 4032);   // 8*5*52=2080
        float* muL = SH + 6112;
        float* invL = SH + 6164;

        int img = g;
        int b = img / QQ;
        const float* X = qry + (size_t)img * CC * HW;
        const float* sg = ws + OFF_SGAP + b * PP * CC;

        for (int i = tid; i < PP * CC / 4; i += 512)
            ((float4*)XSG)[i] = ((const float4*)sg)[i];
        __syncthreads();

        float cs = 0.f, sq = 0.f;
        float acc[PP] = {0.f, 0.f, 0.f, 0.f, 0.f};
        if (lane < HW) {
            for (int c8 = wv * 80; c8 < wv * 80 + 80; c8 += 16) {
                float v[16];
#pragma unroll
                for (int j = 0; j < 16; j++) v[j] = X[(c8 + j) * HW + lane];
#pragma unroll
                for (int j = 0; j < 16; j++) {
                    cs += v[j];
                    sq = fmaf(v[j], v[j], sq);
                }
#pragma unroll
                for (int p = 0; p < PP; p++) {
                    float a = acc[p];
#pragma unroll
                    for (int qv = 0; qv < 4; qv++) {
                        float4 g0 = *(const float4*)&XSG[p * CC + c8 + 4 * qv];
                        a = fmaf(v[4 * qv + 0], g0.x, a);
                        a = fmaf(v[4 * qv + 1], g0.y, a);
                        a = fmaf(v[4 * qv + 2], g0.z, a);
                        a = fmaf(v[4 * qv + 3], g0.w, a);
                    }
                    acc[p] = a;
                }
            }
        }
        if (lane < 52) {
            cs_p[wv][lane] = (lane < HW) ? cs : 0.f;
            sq_p[wv][lane] = (lane < HW) ? sq : 0.f;
#pragma unroll
            for (int p = 0; p < PP; p++) part[wv][p][lane] = (lane < HW) ? acc[p] : 0.f;
        }
        __syncthreads();
        if (wv == 0) {
            if (lane < HW) {
                float c4 = 0.f, s4 = 0.f;
#pragma unroll
                for (int w = 0; w < 8; w++) { c4 += cs_p[w][lane]; s4 += sq_p[w][lane]; }
                float mu = c4 * (1.0f / CC);
                float nsq = fmaxf(s4 - c4 * c4 * (1.0f / CC), 0.f);
                float inv = 1.0f / fmaxf(sqrtf(nsq), 1e-8f);
                ws[OFF_QMEAN + img * HW + lane] = mu;
                ws[OFF_QINV + img * HW + lane] = inv;
                muL[lane] = mu;
                invL[lane] = inv;
            }
#pragma unroll
            for (int p = 0; p < PP; p++) {
                float a = 0.f;
                if (lane < 52) {
#pragma unroll
                    for (int w = 0; w < 8; w++) a += part[w][p][lane];
                }
                float w = (lane < HW) ? (fmaxf(a, 0.f) + 1.01e-3f) : 0.f;
                float s = wsum64(w);
                if (lane < HW) ws[OFF_MARGA + (img * PP + p) * HW + lane] = w / s;
            }
        }
        __syncthreads();
        // pass C: f16 tiles, 32-deep batched
        unsigned* T = (unsigned*)ws + OFF_QT + (size_t)img * TIMG;
        int m = lane;
        if (m < HW) {
            float mu = muL[m], inv = invL[m];
            for (int t = wv; t < CHUNKS; t += 8) {
                float va[32];
#pragma unroll
                for (int j = 0; j < 32; j++) va[j] = X[(t * 32 + j) * HW + m];
                unsigned pk[16];
#pragma unroll
                for (int w = 0; w < 16; w++)
                    pk[w] = packh2((va[2 * w] - mu) * inv, (va[2 * w + 1] - mu) * inv);
                uint4* dst = (uint4*)(T + t * TCH + m * TROW);
#pragma unroll
                for (int u = 0; u < 4; u++)
                    dst[u] = make_uint4(pk[4 * u], pk[4 * u + 1], pk[4 * u + 2], pk[4 * u + 3]);
            }
        }
    } else if (g < 640) {
        // ================= support path: stats + tiles =================
        float (*cs_p)[52] = (float (*)[52])(SH + 3200);
        float (*sq_p)[52] = (float (*)[52])(SH + 3616);
        float* muL = SH + 6112;
        float* invL = SH + 6164;

        int img = g - 600;               // 0..39
        const float* X = sup + (size_t)img * CC * HW;

        float cs = 0.f, sq = 0.f;
        if (lane < HW) {
            for (int c8 = wv * 80; c8 < wv * 80 + 80; c8 += 8) {
                float v[8];
#pragma unroll
                for (int j = 0; j < 8; j++) v[j] = X[(c8 + j) * HW + lane];
#pragma unroll
                for (int j = 0; j < 8; j++) {
                    cs += v[j];
                    sq = fmaf(v[j], v[j], sq);
                }
            }
        }
        if (lane < 52) {
            cs_p[wv][lane] = (lane < HW) ? cs : 0.f;
            sq_p[wv][lane] = (lane < HW) ? sq : 0.f;
        }
        __syncthreads();
        if (wv == 0 && lane < HW) {
            float c4 = 0.f, s4 = 0.f;
#pragma unroll
            for (int w = 0; w < 8; w++) { c4 += cs_p[w][lane]; s4 += sq_p[w][lane]; }
            float mu = c4 * (1.0f / CC);
            float nsq = fmaxf(s4 - c4 * c4 * (1.0f / CC), 0.f);
            float inv = 1.0f / fmaxf(sqrtf(nsq), 1e-8f);
            ws[OFF_SMEAN + img * HW + lane] = mu;
            ws[OFF_SINV + img * HW + lane] = inv;
            muL[lane] = mu;
            invL[lane] = inv;
        }
        __syncthreads();
        unsigned* T = (unsigned*)ws + OFF_ST + (size_t)img * TIMG;
        int m = lane;
        if (m < HW) {
            float mu = muL[m], inv = invL[m];
            for (int t = wv; t < CHUNKS; t += 8) {
                float va[32];
#pragma unroll
                for (int j = 0; j < 32; j++) va[j] = X[(t * 32 + j) * HW + m];
                unsigned pk[16];
#pragma unroll
                for (int w = 0; w < 16; w++)
                    pk[w] = packh2((va[2 * w] - mu) * inv, (va[2 * w + 1] - mu) * inv);
                uint4* dst = (uint4*)(T + t * TCH + m * TROW);
#pragma unroll
                for (int u = 0; u < 4; u++)
                    dst[u] = make_uint4(pk[4 * u], pk[4 * u + 1], pk[4 * u + 2], pk[4 * u + 3]);
            }
        }
    } else {
        // ================= margb path (R12's exact 4-wave math) =================
        int id = g - 640;
        int qc = id % 5;
        int bp = id / 5;
        int b = bp / PP;
        int p = bp % PP;
        const float* X = sup + (size_t)bp * CC * HW;
        const float* qg = ws + OFF_QGAP + (b * QQ + qc * 15) * CC;

        float* QG = SH;                                           // 9600 f
        float (*part)[15][52] = (float (*)[15][52])(SH + 9600);   // 3120 f
        for (int i = tid; i < 15 * CC / 4; i += 512)
            ((float4*)QG)[i] = ((const float4*)qg)[i];
        __syncthreads();

        float acc[15];
#pragma unroll
        for (int i = 0; i < 15; i++) acc[i] = 0.f;
        if (wv < 4 && lane < HW) {
            for (int c8 = wv * 160; c8 < wv * 160 + 160; c8 += 8) {
                float sv[8];
#pragma unroll
                for (int j = 0; j < 8; j++) sv[j] = X[(c8 + j) * HW + lane];
#pragma unroll
                for (int qq = 0; qq < 15; qq++) {
                    float4 g0 = *(const float4*)&QG[qq * CC + c8];
                    float4 g1 = *(const float4*)&QG[qq * CC + c8 + 4];
                    float a = acc[qq];
                    a = fmaf(sv[0], g0.x, a); a = fmaf(sv[1], g0.y, a);
                    a = fmaf(sv[2], g0.z, a); a = fmaf(sv[3], g0.w, a);
                    a = fmaf(sv[4], g1.x, a); a = fmaf(sv[5], g1.y, a);
                    a = fmaf(sv[6], g1.z, a); a = fmaf(sv[7], g1.w, a);
                    acc[qq] = a;
                }
            }
        }
        __syncthreads();
        if (wv < 4 && lane < 52) {
#pragma unroll
            for (int qq = 0; qq < 15; qq++) part[wv][qq][lane] = (lane < HW) ? acc[qq] : 0.f;
        }
        __syncthreads();
        if (wv == 0) {
#pragma unroll
            for (int qq = 0; qq < 15; qq++) {
                float a = 0.f;
                if (lane < 52)
                    a = part[0][qq][lane] + part[1][qq][lane] + part[2][qq][lane] + part[3][qq][lane];
                int q = qc * 15 + qq;
                float w = (lane < HW) ? (fmaxf(a, 0.f) + 1.01e-3f) : 0.f;
                float s = wsum64(w);
                if (lane < HW) ws[OFF_MARGB + ((b * QQ + q) * PP + p) * HW + lane] = w / s;
            }
        }
    }
}

// ---------------- Kernel 2: fused gemm + sinkhorn + logits ----------------
// R14: 5-wave blocks. Waves 0-3 run the R6 MFMA gemm (rows 16wv..16wv+15);
// S stays in LDS. Then wave w runs the R6 all-register sinkhorn for problem
// qi=w, reading K once from LDS with an explicit f16 round-trip (f16r) that
// reproduces the old S16 pack/unpack bit-for-bit -> logits bitwise identical.
// Eliminates the S16 HBM round-trip (30 MB), the sinkhorn launch, and
// overlaps VALU sinkhorn under other blocks' MFMA phases (m114).
#define FOR12(M) M(0) M(1) M(2) M(3) M(4) M(5) M(6) M(7) M(8) M(9) M(10) M(11)
#define KEXPF(s) __expf(fmaf(20.f, (s), -20.f))

__global__ __launch_bounds__(320, 2) void fused_kernel(float* __restrict__ ws) {
    __shared__ unsigned LDSU[CHUNKS * TCH];   // 62.7 KB; reused as S_lds

    int g = blockIdx.x;                // 0..599
    int xcd = g & 7;
    int k = g >> 3;                    // 0..74
    int p = k % 5;
    int gidx = xcd + 8 * (k / 5);      // 0..119  (b,qg) group
    int b = gidx / 15;
    int qg = gidx - b * 15;            // queries qg*5 .. qg*5+4

    int tid = threadIdx.x;
    int lane = tid & 63;
    int wv = tid >> 6;                 // 0..4
    int lrow = lane & 15;
    int quad = lane >> 4;

    // ---- stage B tile (support) into LDS, swizzled (all 320 threads) ----
    const unsigned* Bt = (const unsigned*)ws + OFF_ST + (size_t)(b * PP + p) * TIMG;
    for (int idx = tid; idx < CHUNKS * HW * 4; idx += 320) {
        int r = idx >> 2;
        int q = idx & 3;
        int t = r / 49;
        int n = r - t * 49;
        uint4 v = *(const uint4*)(Bt + (idx << 2));
        *(uint4*)(&LDSU[t * TCH + n * 16 + ((q ^ ((n >> 1) & 3)) << 2)]) = v;
    }
    __syncthreads();

    f32x4 acc[5][4];
    if (wv < 4) {
        int bof[4];
#pragma unroll
        for (int nt = 0; nt < 4; nt++) {
            int n = 16 * nt + lrow;
            if (n > 48) n = 48;
            bof[nt] = n * 16 + ((quad ^ ((n >> 1) & 3)) << 2);
        }
        const unsigned* Aq = (const unsigned*)ws + OFF_QT + (size_t)(b * QQ + qg * 5) * TIMG;
        int arow = (16 * wv + lrow) * TROW + quad * 4;
#pragma unroll
        for (int qi = 0; qi < 5; qi++)
#pragma unroll
            for (int nt = 0; nt < 4; nt++) acc[qi][nt] = (f32x4){0.f, 0.f, 0.f, 0.f};
#pragma unroll 2
        for (int t = 0; t < CHUNKS; t++) {
            f16x8 bfr[4];
#pragma unroll
            for (int nt = 0; nt < 4; nt++)
                bfr[nt] = *(const f16x8*)(&LDSU[t * TCH + bof[nt]]);
#pragma unroll
            for (int qi = 0; qi < 5; qi++) {
                f16x8 a = *(const f16x8*)(Aq + (size_t)qi * TIMG + t * TCH + arow);
#pragma unroll
                for (int nt = 0; nt < 4; nt++)
                    acc[qi][nt] = MFMAH(a, bfr[nt], acc[qi][nt], 0, 0, 0);
            }
        }
    }
    __syncthreads();                       // all B reads done
    float* S_lds = (float*)LDSU;           // 5 * 2597 = 12985 f32 < 15680
    if (wv < 4) {
        // C/D layout: col = lane&15, row = quad*4 + reg (m89)
#pragma unroll
        for (int qi = 0; qi < 5; qi++)
#pragma unroll
            for (int nt = 0; nt < 4; nt++)
#pragma unroll
                for (int r = 0; r < 4; r++) {
                    int mm = 16 * wv + quad * 4 + r;
                    int nn = 16 * nt + lrow;
                    if (mm < HW && nn < HW) S_lds[qi * 2597 + mm * 53 + nn] = acc[qi][nt][r];
                }
    }
    __syncthreads();

    // ---- fused sinkhorn: wave wv handles problem qi = wv ----
    int qi = wv;
    int prob = (b * QQ + qg * 5 + qi) * PP + p;
    const float* Sq = S_lds + qi * 2597;

    float am = 0.f, bm = 0.f;
    if (lane < HW) {
        am = ws[OFF_MARGA + prob * HW + lane];
        bm = ws[OFF_MARGB + prob * HW + lane];
    }
    int ll = (lane < HW) ? lane : 48;
    const float* Srow = Sq + ll * 53;      // row ll of S

    float4 kr0, kr1, kr2, kr3, kr4, kr5, kr6, kr7, kr8, kr9, kr10, kr11;
    float4 kt0, kt1, kt2, kt3, kt4, kt5, kt6, kt7, kt8, kt9, kt10, kt11;
    float kr12x, kt12x;
#define KIR(g) kr##g = make_float4(KEXPF(f16r(Srow[4*(g)+0])), KEXPF(f16r(Srow[4*(g)+1])), \
                                   KEXPF(f16r(Srow[4*(g)+2])), KEXPF(f16r(Srow[4*(g)+3])));
    FOR12(KIR)
#undef KIR
    kr12x = KEXPF(f16r(Srow[48]));
#define KIT(g) kt##g = make_float4(KEXPF(f16r(Sq[(4*(g)+0)*53 + ll])), KEXPF(f16r(Sq[(4*(g)+1)*53 + ll])), \
                                   KEXPF(f16r(Sq[(4*(g)+2)*53 + ll])), KEXPF(f16r(Sq[(4*(g)+3)*53 + ll])));
    FOR12(KIT)
#undef KIT
    kt12x = KEXPF(f16r(Sq[48 * 53 + ll]));

    float vv = (lane < HW) ? 1.f : 0.f;
    float uu = 0.f;

#pragma unroll 1
    for (int it = 0; it < 48; it++) {
        float t0 = 0.f, t1 = 0.f, t2 = 0.f, t3 = 0.f;
#define RS(g) { t0 = fmaf(kr##g.x, rlf(vv, 4*(g)+0), t0);                   \
                t1 = fmaf(kr##g.y, rlf(vv, 4*(g)+1), t1);                   \
                t2 = fmaf(kr##g.z, rlf(vv, 4*(g)+2), t2);                   \
                t3 = fmaf(kr##g.w, rlf(vv, 4*(g)+3), t3); }
        FOR12(RS)
#undef RS
        t0 = fmaf(kr12x, rlf(vv, 48), t0);
        float t = (t0 + t1) + (t2 + t3);
        uu = am * __builtin_amdgcn_rcpf(t);

        float s0 = 0.f, s1 = 0.f, s2 = 0.f, s3 = 0.f;
#define CS(g) { s0 = fmaf(kt##g.x, rlf(uu, 4*(g)+0), s0);                   \
                s1 = fmaf(kt##g.y, rlf(uu, 4*(g)+1), s1);                   \
                s2 = fmaf(kt##g.z, rlf(uu, 4*(g)+2), s2);                   \
                s3 = fmaf(kt##g.w, rlf(uu, 4*(g)+3), s3); }
        FOR12(CS)
#undef CS
        s0 = fmaf(kt12x, rlf(uu, 48), s0);
        float s = (s0 + s1) + (s2 + s3);
        vv = bm * __builtin_amdgcn_rcpf(s);
    }

    // logit = T * sum S*P with S = 1 + 0.05*ln(K)
    float ssum = 0.f;
#define FS(g) {                                                             \
    ssum = fmaf(kr##g.x * fmaf(0.05f, __logf(kr##g.x), 1.f), rlf(vv, 4*(g)+0), ssum); \
    ssum = fmaf(kr##g.y * fmaf(0.05f, __logf(kr##g.y), 1.f), rlf(vv, 4*(g)+1), ssum); \
    ssum = fmaf(kr##g.z * fmaf(0.05f, __logf(kr##g.z), 1.f), rlf(vv, 4*(g)+2), ssum); \
    ssum = fmaf(kr##g.w * fmaf(0.05f, __logf(kr##g.w), 1.f), rlf(vv, 4*(g)+3), ssum); }
    FOR12(FS)
#undef FS
    ssum = fmaf(kr12x * fmaf(0.05f, __logf(kr12x), 1.f), rlf(vv, 48), ssum);
    float contrib = (lane < HW) ? (uu * ssum) : 0.f;
    float tot = wsum64(contrib);
    if (lane == 0) ws[OFF_LOGITS + prob] = TEMP * tot;
}

// ---------------- Kernel 5: cross-entropy loss ----------------
__global__ __launch_bounds__(640) void loss_kernel(const float* __restrict__ ws,
                                                   const int* __restrict__ qy,
                                                   float* __restrict__ out) {
    int tid = threadIdx.x;
    float val = 0.f;
    if (tid < NIMG_Q) {
        const float* lg = ws + OFF_LOGITS + tid * PP;
        float l[PP];
        float mx = -1e30f;
#pragma unroll
        for (int p = 0; p < PP; p++) {
            l[p] = lg[p];
            mx = fmaxf(mx, l[p]);
        }
        float se = 0.f;
#pragma unroll
        for (int p = 0; p < PP; p++) se += __expf(l[p] - mx);
        float lse = mx + logf(se);
        int lab = qy[tid];
        val = -(l[lab] - lse);
    }
    __shared__ float red[16];
    float s = wsum64(val);
    if ((tid & 63) == 0) red[tid >> 6] = s;
    __syncthreads();
    if (tid == 0) {
        float tot = 0.f;
#pragma unroll
        for (int w = 0; w < 10; w++) tot += red[w];
        out[0] = tot * (1.0f / NIMG_Q);
    }
}

extern "C" void kernel_launch(void* const* d_in, const int* in_sizes, int n_in,
                              void* d_out, int out_size, void* d_ws, size_t ws_size,
                              hipStream_t stream) {
    const float* sup = (const float*)d_in[0];   // support_xf [8,5,640,7,7]
    const float* qry = (const float*)d_in[1];   // query_xf   [8,75,640,7,7]
    const int* qy = (const int*)d_in[3];        // query_y    [8,75]
    float* ws = (float*)d_ws;
    float* out = (float*)d_out;

    gap_kernel<<<640, 256, 0, stream>>>(sup, qry, ws);
    prep_kernel<<<840, 512, 0, stream>>>(sup, qry, ws);
    fused_kernel<<<600, 320, 0, stream>>>(ws);
    loss_kernel<<<1, 640, 0, stream>>>(ws, qy, out);
}

// Round 15
// 260.710 us; speedup vs baseline: 1.1616x; 1.1616x over previous
//
#include <hip/hip_runtime.h>
#include <math.h>

#define BB 8
#define PP 5
#define QQ 75
#define CC 640
#define HW 49
#define NIMG_Q (BB*QQ)     // 600
#define NIMG_S (BB*PP)     // 40
#define NPROB  (BB*QQ*PP)  // 3000
#define TEMP 12.5f

#define CHUNKS 20          // 640 / 32
#define TROW 16            // u32 per tile row (32 f16)
#define TCH  (HW*TROW)     // 784 u32 per chunk
#define TIMG (CHUNKS*TCH)  // 15680 u32 per image
#define SROW 25            // u32 per S row (50 f16, last is zero pad)
#define SPROB (HW*SROW)    // 1225 u32 per problem

// workspace layout (u32/float offsets); total ~14.48M words = 57.9 MB
#define OFF_SGAP   0
#define OFF_QGAP   (OFF_SGAP  + NIMG_S*CC)
#define OFF_SMEAN  (OFF_QGAP  + NIMG_Q*CC)
#define OFF_SINV   (OFF_SMEAN + NIMG_S*HW)
#define OFF_QMEAN  (OFF_SINV  + NIMG_S*HW)
#define OFF_QINV   (OFF_QMEAN + NIMG_Q*HW)
#define OFF_MARGA  (OFF_QINV  + NIMG_Q*HW)
#define OFF_MARGB  (OFF_MARGA + NPROB*HW)
#define OFF_QT     (OFF_MARGB + NPROB*HW)          // query f16 tiles
#define OFF_ST     (OFF_QT    + NIMG_Q*TIMG)       // support f16 tiles
#define OFF_S16    (OFF_ST    + NIMG_S*TIMG)       // S matrices, f16 packed
#define OFF_LOGITS (OFF_S16   + NPROB*SPROB)

typedef _Float16 f16x8 __attribute__((ext_vector_type(8)));
typedef float f32x4 __attribute__((ext_vector_type(4)));
#define MFMAH __builtin_amdgcn_mfma_f32_16x16x32_f16

__device__ __forceinline__ float wsum64(float v) {
#pragma unroll
    for (int off = 32; off > 0; off >>= 1) v += __shfl_xor(v, off, 64);
    return v;
}
__device__ __forceinline__ float rlf(float x, int l) {
    return __int_as_float(__builtin_amdgcn_readlane(__float_as_int(x), l));
}
__device__ __forceinline__ unsigned packh2(float a, float b) {
    union { _Float16 h[2]; unsigned u; } pk;
    pk.h[0] = (_Float16)a; pk.h[1] = (_Float16)b;
    return pk.u;
}
__device__ __forceinline__ float f16lo(unsigned w) {
    union { unsigned short s; _Float16 h; } u; u.s = (unsigned short)w; return (float)u.h;
}
__device__ __forceinline__ float f16hi(unsigned w) {
    union { unsigned short s; _Float16 h; } u; u.s = (unsigned short)(w >> 16); return (float)u.h;
}

// ---------------- Kernel 0: support GAP pre-pass ----------------
__global__ __launch_bounds__(256) void sgap_kernel(const float* __restrict__ sup,
                                                   float* __restrict__ ws) {
    int img = blockIdx.x;              // 0..39
    int tid = threadIdx.x;
    const float* X = sup + (size_t)img * CC * HW;
    float* gap = ws + OFF_SGAP + img * CC;
    for (int c = tid; c < CC; c += 256) {
        const float* row = X + c * HW;
        float s = 0.f;
#pragma unroll
        for (int g = 0; g < 6; g++) {
            float rv[8];
#pragma unroll
            for (int j = 0; j < 8; j++) rv[j] = row[g * 8 + j];
#pragma unroll
            for (int j = 0; j < 8; j++) s += rv[j];
        }
        s += row[48];
        gap[c] = s * (1.0f / HW);
    }
}

// ---------------- Kernel 1: merged prep: qry (0..599) + sup rest (600..639) --
// (R13 structure, verified 258.4us)
__global__ __launch_bounds__(512) __attribute__((amdgpu_waves_per_eu(4, 4)))
void prep_kernel(const float* __restrict__ sup, const float* __restrict__ qry,
                 float* __restrict__ ws) {
    int g = blockIdx.x;
    int tid = threadIdx.x;
    int lane = tid & 63;
    int wv = tid >> 6;               // 0..7

    __shared__ float XSG[PP * CC];   // 12.8 KB (qry path only)
    __shared__ float cs_p[8][52], sq_p[8][52];
    __shared__ float part[8][PP][52];
    __shared__ float muL[52], invL[52];

    if (g < 600) {
        // ================= query path =================
        int img = g;
        int b = img / QQ;
        const float* X = qry + (size_t)img * CC * HW;
        const float* sg = ws + OFF_SGAP + b * PP * CC;
        float* gap = ws + OFF_QGAP + img * CC;

        for (int i = tid; i < PP * CC / 4; i += 512)
            ((float4*)XSG)[i] = ((const float4*)sg)[i];
        __syncthreads();

        float cs = 0.f, sq = 0.f;
        float acc[PP] = {0.f, 0.f, 0.f, 0.f, 0.f};
        if (lane < HW) {
            for (int c8 = wv * 80; c8 < wv * 80 + 80; c8 += 16) {
                float v[16];
#pragma unroll
                for (int j = 0; j < 16; j++) v[j] = X[(c8 + j) * HW + lane];
#pragma unroll
                for (int j = 0; j < 16; j++) {
                    cs += v[j];
                    sq = fmaf(v[j], v[j], sq);
                }
#pragma unroll
                for (int p = 0; p < PP; p++) {
                    float a = acc[p];
#pragma unroll
                    for (int qv = 0; qv < 4; qv++) {
                        float4 g0 = *(const float4*)&XSG[p * CC + c8 + 4 * qv];
                        a = fmaf(v[4 * qv + 0], g0.x, a);
                        a = fmaf(v[4 * qv + 1], g0.y, a);
                        a = fmaf(v[4 * qv + 2], g0.z, a);
                        a = fmaf(v[4 * qv + 3], g0.w, a);
                    }
                    acc[p] = a;
                }
            }
        }
        if (lane < 52) {
            cs_p[wv][lane] = (lane < HW) ? cs : 0.f;
            sq_p[wv][lane] = (lane < HW) ? sq : 0.f;
#pragma unroll
            for (int p = 0; p < PP; p++) part[wv][p][lane] = (lane < HW) ? acc[p] : 0.f;
        }
        __syncthreads();
        if (wv == 0) {
            if (lane < HW) {
                float c4 = 0.f, s4 = 0.f;
#pragma unroll
                for (int w = 0; w < 8; w++) { c4 += cs_p[w][lane]; s4 += sq_p[w][lane]; }
                float mu = c4 * (1.0f / CC);
                float nsq = fmaxf(s4 - c4 * c4 * (1.0f / CC), 0.f);
                float inv = 1.0f / fmaxf(sqrtf(nsq), 1e-8f);
                ws[OFF_QMEAN + img * HW + lane] = mu;
                ws[OFF_QINV + img * HW + lane] = inv;
                muL[lane] = mu;
                invL[lane] = inv;
            }
#pragma unroll
            for (int p = 0; p < PP; p++) {
                float a = 0.f;
                if (lane < 52) {
#pragma unroll
                    for (int w = 0; w < 8; w++) a += part[w][p][lane];
                }
                float w = (lane < HW) ? (fmaxf(a, 0.f) + 1.01e-3f) : 0.f;
                float s = wsum64(w);
                if (lane < HW) ws[OFF_MARGA + (img * PP + p) * HW + lane] = w / s;
            }
        }
        // pass B: GAP, 8-deep batched
        for (int c = tid; c < CC; c += 512) {
            const float* row = X + c * HW;
            float s = 0.f;
#pragma unroll
            for (int gg = 0; gg < 6; gg++) {
                float rv[8];
#pragma unroll
                for (int j = 0; j < 8; j++) rv[j] = row[gg * 8 + j];
#pragma unroll
                for (int j = 0; j < 8; j++) s += rv[j];
            }
            s += row[48];
            gap[c] = s * (1.0f / HW);
        }
        __syncthreads();
        // pass C: f16 tiles, 32-deep batched
        unsigned* T = (unsigned*)ws + OFF_QT + (size_t)img * TIMG;
        int m = lane;
        if (m < HW) {
            float mu = muL[m], inv = invL[m];
            for (int t = wv; t < CHUNKS; t += 8) {
                float va[32];
#pragma unroll
                for (int j = 0; j < 32; j++) va[j] = X[(t * 32 + j) * HW + m];
                unsigned pk[16];
#pragma unroll
                for (int w = 0; w < 16; w++)
                    pk[w] = packh2((va[2 * w] - mu) * inv, (va[2 * w + 1] - mu) * inv);
                uint4* dst = (uint4*)(T + t * TCH + m * TROW);
#pragma unroll
                for (int u = 0; u < 4; u++)
                    dst[u] = make_uint4(pk[4 * u], pk[4 * u + 1], pk[4 * u + 2], pk[4 * u + 3]);
            }
        }
    } else {
        // ============ support path: stats + tiles (gap done by sgap) ============
        int img = g - 600;               // 0..39
        const float* X = sup + (size_t)img * CC * HW;

        float cs = 0.f, sq = 0.f;
        if (lane < HW) {
            for (int c8 = wv * 80; c8 < wv * 80 + 80; c8 += 8) {
                float v[8];
#pragma unroll
                for (int j = 0; j < 8; j++) v[j] = X[(c8 + j) * HW + lane];
#pragma unroll
                for (int j = 0; j < 8; j++) {
                    cs += v[j];
                    sq = fmaf(v[j], v[j], sq);
                }
            }
        }
        if (lane < 52) {
            cs_p[wv][lane] = (lane < HW) ? cs : 0.f;
            sq_p[wv][lane] = (lane < HW) ? sq : 0.f;
        }
        __syncthreads();
        if (wv == 0 && lane < HW) {
            float c4 = 0.f, s4 = 0.f;
#pragma unroll
            for (int w = 0; w < 8; w++) { c4 += cs_p[w][lane]; s4 += sq_p[w][lane]; }
            float mu = c4 * (1.0f / CC);
            float nsq = fmaxf(s4 - c4 * c4 * (1.0f / CC), 0.f);
            float inv = 1.0f / fmaxf(sqrtf(nsq), 1e-8f);
            ws[OFF_SMEAN + img * HW + lane] = mu;
            ws[OFF_SINV + img * HW + lane] = inv;
            muL[lane] = mu;
            invL[lane] = inv;
        }
        __syncthreads();                   // muL/invL visible before pass C
        unsigned* T = (unsigned*)ws + OFF_ST + (size_t)img * TIMG;
        int m = lane;
        if (m < HW) {
            float mu = muL[m], inv = invL[m];
            for (int t = wv; t < CHUNKS; t += 8) {
                float va[32];
#pragma unroll
                for (int j = 0; j < 32; j++) va[j] = X[(t * 32 + j) * HW + m];
                unsigned pk[16];
#pragma unroll
                for (int w = 0; w < 16; w++)
                    pk[w] = packh2((va[2 * w] - mu) * inv, (va[2 * w + 1] - mu) * inv);
                uint4* dst = (uint4*)(T + t * TCH + m * TROW);
#pragma unroll
                for (int u = 0; u < 4; u++)
                    dst[u] = make_uint4(pk[4 * u], pk[4 * u + 1], pk[4 * u + 2], pk[4 * u + 3]);
            }
        }
    }
}

// ---------------- Kernel 3: fused gemm (0..599) + margb (600..799), 512 thr --
// R15: gemm phase was 2 waves/SIMD (62.7KB LDS -> 2 blocks/CU x 4 waves);
// latency of the 5 A-loads per chunk was exposed. Now 8 waves/block: wave w
// owns row-group (w&3) and col-half (w>>2) -> acc[5][2], 10 MFMAs per chunk.
// Per-output accumulation order unchanged (chunk-ascending, same MFMA seq)
// -> bitwise-identical S. 16 waves/CU = 4/SIMD doubles latency hiding.
// A-loads duplicated across col-half wave pairs (L1-hot, cheap).
__global__ __launch_bounds__(512, 2) void mgemm_kernel(const float* __restrict__ sup,
                                                       float* __restrict__ ws) {
    __shared__ unsigned LDSU[CHUNKS * TCH];   // 15680 u32 = 62.7 KB

    int g = blockIdx.x;
    int tid = threadIdx.x;
    int lane = tid & 63;
    int wv = tid >> 6;                 // 0..7

    if (g < 600) {
        // ================= GEMM path =================
        int xcd = g & 7;
        int k = g >> 3;                    // 0..74
        int p = k % 5;
        int gidx = xcd + 8 * (k / 5);      // 0..119  (b,qg) group
        int b = gidx / 15;
        int qg = gidx - b * 15;            // queries qg*5 .. qg*5+4
        int lrow = lane & 15;
        int quad = lane >> 4;
        int wr = wv & 3;                   // row group 0..3
        int wh = wv >> 2;                  // col half 0..1

        const unsigned* Bt = (const unsigned*)ws + OFF_ST + (size_t)(b * PP + p) * TIMG;
        for (int idx = tid; idx < CHUNKS * HW * 4; idx += 512) {   // 3920 x 16B
            int r = idx >> 2;
            int q = idx & 3;
            int t = r / 49;
            int n = r - t * 49;
            uint4 v = *(const uint4*)(Bt + (idx << 2));
            *(uint4*)(&LDSU[t * TCH + n * 16 + ((q ^ ((n >> 1) & 3)) << 2)]) = v;
        }
        __syncthreads();

        int bof[2];
#pragma unroll
        for (int nt2 = 0; nt2 < 2; nt2++) {
            int n = 16 * (wh * 2 + nt2) + lrow;
            if (n > 48) n = 48;
            bof[nt2] = n * 16 + ((quad ^ ((n >> 1) & 3)) << 2);
        }

        const unsigned* Aq = (const unsigned*)ws + OFF_QT + (size_t)(b * QQ + qg * 5) * TIMG;
        int arow = (16 * wr + lrow) * TROW + quad * 4;

        f32x4 acc[5][2];
#pragma unroll
        for (int qi = 0; qi < 5; qi++)
#pragma unroll
            for (int nt2 = 0; nt2 < 2; nt2++) acc[qi][nt2] = (f32x4){0.f, 0.f, 0.f, 0.f};

#pragma unroll 2
        for (int t = 0; t < CHUNKS; t++) {
            f16x8 bfr[2];
#pragma unroll
            for (int nt2 = 0; nt2 < 2; nt2++)
                bfr[nt2] = *(const f16x8*)(&LDSU[t * TCH + bof[nt2]]);
#pragma unroll
            for (int qi = 0; qi < 5; qi++) {
                f16x8 a = *(const f16x8*)(Aq + (size_t)qi * TIMG + t * TCH + arow);
#pragma unroll
                for (int nt2 = 0; nt2 < 2; nt2++)
                    acc[qi][nt2] = MFMAH(a, bfr[nt2], acc[qi][nt2], 0, 0, 0);
            }
        }

        __syncthreads();                       // all B reads done
        float* S_lds = (float*)LDSU;           // 5 * 2597 = 12985 f32 < 15680
        // C/D layout: col = lane&15, row = quad*4 + reg (dtype-independent, m89)
#pragma unroll
        for (int qi = 0; qi < 5; qi++)
#pragma unroll
            for (int nt2 = 0; nt2 < 2; nt2++)
#pragma unroll
                for (int r = 0; r < 4; r++) {
                    int mm = 16 * wr + quad * 4 + r;
                    int nn = 16 * (wh * 2 + nt2) + lrow;
                    if (mm < HW && nn < HW) S_lds[qi * 2597 + mm * 53 + nn] = acc[qi][nt2][r];
                }
        __syncthreads();

        for (int qi = 0; qi < 5; qi++) {
            int prob = (b * QQ + qg * 5 + qi) * PP + p;
            unsigned* Sp = (unsigned*)ws + OFF_S16 + (size_t)prob * SPROB;
            const float* Sl = S_lds + qi * 2597;
            for (int idx = tid; idx < SPROB; idx += 512) {
                int row = idx / SROW;
                int w = idx - row * SROW;
                int n0 = 2 * w;
                float v0 = Sl[row * 53 + n0];
                float v1 = (n0 + 1 < HW) ? Sl[row * 53 + n0 + 1] : 0.f;
                Sp[idx] = packh2(v0, v1);
            }
        }
    } else {
        // ============ margb path (R12 math; waves 4..7 idle through barriers) ===
        int id = g - 600;
        int qc = id % 5;
        int bp = id / 5;
        int b = bp / PP;
        int p = bp % PP;
        const float* X = sup + (size_t)bp * CC * HW;
        const float* qg = ws + OFF_QGAP + (b * QQ + qc * 15) * CC;

        float* QG = (float*)LDSU;                                   // 9600 f
        float (*part)[15][52] = (float (*)[15][52])((float*)LDSU + 15 * CC); // 3120 f
        for (int i = tid; i < 15 * CC / 4; i += 512)
            ((float4*)QG)[i] = ((const float4*)qg)[i];
        __syncthreads();

        float acc[15];
#pragma unroll
        for (int i = 0; i < 15; i++) acc[i] = 0.f;
        if (wv < 4 && lane < HW) {
            for (int c8 = wv * 160; c8 < wv * 160 + 160; c8 += 8) {
                float sv[8];
#pragma unroll
                for (int j = 0; j < 8; j++) sv[j] = X[(c8 + j) * HW + lane];
#pragma unroll
                for (int qq = 0; qq < 15; qq++) {
                    float4 g0 = *(const float4*)&QG[qq * CC + c8];
                    float4 g1 = *(const float4*)&QG[qq * CC + c8 + 4];
                    float a = acc[qq];
                    a = fmaf(sv[0], g0.x, a); a = fmaf(sv[1], g0.y, a);
                    a = fmaf(sv[2], g0.z, a); a = fmaf(sv[3], g0.w, a);
                    a = fmaf(sv[4], g1.x, a); a = fmaf(sv[5], g1.y, a);
                    a = fmaf(sv[6], g1.z, a); a = fmaf(sv[7], g1.w, a);
                    acc[qq] = a;
                }
            }
        }
        __syncthreads();
        if (wv < 4 && lane < 52) {
#pragma unroll
            for (int qq = 0; qq < 15; qq++) part[wv][qq][lane] = (lane < HW) ? acc[qq] : 0.f;
        }
        __syncthreads();
        if (wv == 0) {
#pragma unroll
            for (int qq = 0; qq < 15; qq++) {
                float a = 0.f;
                if (lane < 52)
                    a = part[0][qq][lane] + part[1][qq][lane] + part[2][qq][lane] + part[3][qq][lane];
                int q = qc * 15 + qq;
                float w = (lane < HW) ? (fmaxf(a, 0.f) + 1.01e-3f) : 0.f;
                float s = wsum64(w);
                if (lane < HW) ws[OFF_MARGB + ((b * QQ + q) * PP + p) * HW + lane] = w / s;
            }
        }
    }
}

// ---------------- Kernel 4b: Sinkhorn + logit, one wave per problem ----------
// R6 all-register structure (best measured 56.6us). R7 LDS-KT, R9 opq-pin,
// R10 2-wave split, R14 gemm-fusion all failed -> treat as practical floor.
#define FOR12(M) M(0) M(1) M(2) M(3) M(4) M(5) M(6) M(7) M(8) M(9) M(10) M(11)
#define KEXPF(s) __expf(fmaf(20.f, (s), -20.f))

__global__ __launch_bounds__(64)
__attribute__((amdgpu_waves_per_eu(3, 3)))
void sinkhorn_kernel(float* __restrict__ ws) {
    int prob = blockIdx.x;
    int lane = threadIdx.x;
    const unsigned* Sp = (const unsigned*)ws + OFF_S16 + (size_t)prob * SPROB;

    float am = 0.f, bm = 0.f;
    if (lane < HW) {
        am = ws[OFF_MARGA + prob * HW + lane];
        bm = ws[OFF_MARGB + prob * HW + lane];
    }
    int ll = (lane < HW) ? lane : 48;
    const unsigned* rbase = Sp + ll * SROW;       // row ll of S (f16 pairs)
    int wof = ll >> 1;
    int sh = (ll & 1) * 16;

    float4 kr0, kr1, kr2, kr3, kr4, kr5, kr6, kr7, kr8, kr9, kr10, kr11;
    float4 kt0, kt1, kt2, kt3, kt4, kt5, kt6, kt7, kt8, kt9, kt10, kt11;
    float kr12x, kt12x;
#define KIR(g) { unsigned w0 = rbase[2*(g)]; unsigned w1 = rbase[2*(g)+1];  \
    kr##g = make_float4(KEXPF(f16lo(w0)), KEXPF(f16hi(w0)),                 \
                        KEXPF(f16lo(w1)), KEXPF(f16hi(w1))); }
    FOR12(KIR)
#undef KIR
    kr12x = KEXPF(f16lo(rbase[24]));
#define KIT(g) { \
    float s0 = f16lo((Sp[(4*(g)+0)*SROW + wof] >> sh) & 0xFFFFu);           \
    float s1 = f16lo((Sp[(4*(g)+1)*SROW + wof] >> sh) & 0xFFFFu);           \
    float s2 = f16lo((Sp[(4*(g)+2)*SROW + wof] >> sh) & 0xFFFFu);           \
    float s3 = f16lo((Sp[(4*(g)+3)*SROW + wof] >> sh) & 0xFFFFu);           \
    kt##g = make_float4(KEXPF(s0), KEXPF(s1), KEXPF(s2), KEXPF(s3)); }
    FOR12(KIT)
#undef KIT
    kt12x = KEXPF(f16lo((Sp[48 * SROW + wof] >> sh) & 0xFFFFu));

    float vv = (lane < HW) ? 1.f : 0.f;
    float uu = 0.f;

#pragma unroll 1
    for (int it = 0; it < 48; it++) {
        float t0 = 0.f, t1 = 0.f, t2 = 0.f, t3 = 0.f;
#define RS(g) { t0 = fmaf(kr##g.x, rlf(vv, 4*(g)+0), t0);                   \
                t1 = fmaf(kr##g.y, rlf(vv, 4*(g)+1), t1);                   \
                t2 = fmaf(kr##g.z, rlf(vv, 4*(g)+2), t2);                   \
                t3 = fmaf(kr##g.w, rlf(vv, 4*(g)+3), t3); }
        FOR12(RS)
#undef RS
        t0 = fmaf(kr12x, rlf(vv, 48), t0);
        float t = (t0 + t1) + (t2 + t3);
        uu = am * __builtin_amdgcn_rcpf(t);

        float s0 = 0.f, s1 = 0.f, s2 = 0.f, s3 = 0.f;
#define CS(g) { s0 = fmaf(kt##g.x, rlf(uu, 4*(g)+0), s0);                   \
                s1 = fmaf(kt##g.y, rlf(uu, 4*(g)+1), s1);                   \
                s2 = fmaf(kt##g.z, rlf(uu, 4*(g)+2), s2);                   \
                s3 = fmaf(kt##g.w, rlf(uu, 4*(g)+3), s3); }
        FOR12(CS)
#undef CS
        s0 = fmaf(kt12x, rlf(uu, 48), s0);
        float s = (s0 + s1) + (s2 + s3);
        vv = bm * __builtin_amdgcn_rcpf(s);
    }

    // logit = T * sum S*P with S = 1 + 0.05*ln(K)
    float ssum = 0.f;
#define FS(g) {                                                             \
    ssum = fmaf(kr##g.x * fmaf(0.05f, __logf(kr##g.x), 1.f), rlf(vv, 4*(g)+0), ssum); \
    ssum = fmaf(kr##g.y * fmaf(0.05f, __logf(kr##g.y), 1.f), rlf(vv, 4*(g)+1), ssum); \
    ssum = fmaf(kr##g.z * fmaf(0.05f, __logf(kr##g.z), 1.f), rlf(vv, 4*(g)+2), ssum); \
    ssum = fmaf(kr##g.w * fmaf(0.05f, __logf(kr##g.w), 1.f), rlf(vv, 4*(g)+3), ssum); }
    FOR12(FS)
#undef FS
    ssum = fmaf(kr12x * fmaf(0.05f, __logf(kr12x), 1.f), rlf(vv, 48), ssum);
    float contrib = (lane < HW) ? (uu * ssum) : 0.f;
    float tot = wsum64(contrib);
    if (lane == 0) ws[OFF_LOGITS + prob] = TEMP * tot;
}

// ---------------- Kernel 5: cross-entropy loss ----------------
__global__ __launch_bounds__(640) void loss_kernel(const float* __restrict__ ws,
                                                   const int* __restrict__ qy,
                                                   float* __restrict__ out) {
    int tid = threadIdx.x;
    float val = 0.f;
    if (tid < NIMG_Q) {
        const float* lg = ws + OFF_LOGITS + tid * PP;
        float l[PP];
        float mx = -1e30f;
#pragma unroll
        for (int p = 0; p < PP; p++) {
            l[p] = lg[p];
            mx = fmaxf(mx, l[p]);
        }
        float se = 0.f;
#pragma unroll
        for (int p = 0; p < PP; p++) se += __expf(l[p] - mx);
        float lse = mx + logf(se);
        int lab = qy[tid];
        val = -(l[lab] - lse);
    }
    __shared__ float red[16];
    float s = wsum64(val);
    if ((tid & 63) == 0) red[tid >> 6] = s;
    __syncthreads();
    if (tid == 0) {
        float tot = 0.f;
#pragma unroll
        for (int w = 0; w < 10; w++) tot += red[w];
        out[0] = tot * (1.0f / NIMG_Q);
    }
}

extern "C" void kernel_launch(void* const* d_in, const int* in_sizes, int n_in,
                              void* d_out, int out_size, void* d_ws, size_t ws_size,
                              hipStream_t stream) {
    const float* sup = (const float*)d_in[0];   // support_xf [8,5,640,7,7]
    const float* qry = (const float*)d_in[1];   // query_xf   [8,75,640,7,7]
    const int* qy = (const int*)d_in[3];        // query_y    [8,75]
    float* ws = (float*)d_ws;
    float* out = (float*)d_out;

    sgap_kernel<<<NIMG_S, 256, 0, stream>>>(sup, ws);
    prep_kernel<<<640, 512, 0, stream>>>(sup, qry, ws);
    mgemm_kernel<<<800, 512, 0, stream>>>(sup, ws);
    sinkhorn_kernel<<<NPROB, 64, 0, stream>>>(ws);
    loss_kernel<<<1, 640, 0, stream>>>(ws, qy, out);
}